// Round 6
// baseline (346.838 us; speedup 1.0000x reference)
//
#include <hip/hip_runtime.h>
#include <hip/hip_bf16.h>
#include <stdint.h>

// Problem constants (reference: LoRA adapter forward)
#define TOKENS   8192
#define DIM      4096
#define DIM_OUT  4096
#define LORA_R   16
#define LORA_SCALE 2.0f

typedef __bf16 bf16_t;
typedef __attribute__((ext_vector_type(8))) __bf16 bfrag;    // 8 bf16 = 4 VGPR
typedef __attribute__((ext_vector_type(16))) float f32x16;   // 32x32 MFMA C/D frag

// ---------------------------------------------------------------------------
// async global->LDS, 16B per lane (global_load_lds_dwordx4)
// ---------------------------------------------------------------------------
__device__ __forceinline__ void gload_lds16(const bf16_t* gsrc, bf16_t* ldst) {
    __builtin_amdgcn_global_load_lds(
        (const __attribute__((address_space(1))) uint32_t*)(const void*)gsrc,
        (__attribute__((address_space(3))) uint32_t*)(void*)ldst,
        16, 0, 0);
}

// ---------------------------------------------------------------------------
// Kernel 1: cast x (fp32) -> bf16, 8 elems/thread, grid-stride  (R3-validated)
// ---------------------------------------------------------------------------
__global__ void cast_x_kernel(const float* __restrict__ x, bf16_t* __restrict__ xb) {
    const int total = TOKENS * DIM / 8;
    for (int i = blockIdx.x * blockDim.x + threadIdx.x; i < total;
         i += gridDim.x * blockDim.x) {
        const float4* p = reinterpret_cast<const float4*>(x + (size_t)i * 8);
        float4 v0 = p[0], v1 = p[1];
        union { bf16_t o[8]; uint4 u; } pk;
        pk.o[0] = (bf16_t)v0.x; pk.o[1] = (bf16_t)v0.y;
        pk.o[2] = (bf16_t)v0.z; pk.o[3] = (bf16_t)v0.w;
        pk.o[4] = (bf16_t)v1.x; pk.o[5] = (bf16_t)v1.y;
        pk.o[6] = (bf16_t)v1.z; pk.o[7] = (bf16_t)v1.w;
        *reinterpret_cast<uint4*>(xb + (size_t)i * 8) = pk.u;
    }
}

// ---------------------------------------------------------------------------
// Kernel 2: Weff_t[n][k] = W[n][k] + SCALE*sum_r A[k][r]B[r][n]  (R3-validated)
// ---------------------------------------------------------------------------
__global__ void weff_kernel(const float* __restrict__ W, const float* __restrict__ A,
                            const float* __restrict__ B, bf16_t* __restrict__ Wt) {
    int idx = blockIdx.x * blockDim.x + threadIdx.x;   // DIM_OUT*DIM/32 threads
    int k0 = (idx & 511) << 3;          // 512 k-groups of 8
    int n0 = (idx >> 9) << 2;           // 1024 n-groups of 4

    float bn[4][16];
#pragma unroll
    for (int r = 0; r < 16; ++r) {
        float4 bv = *reinterpret_cast<const float4*>(B + (size_t)r * DIM_OUT + n0);
        bn[0][r] = bv.x; bn[1][r] = bv.y; bn[2][r] = bv.z; bn[3][r] = bv.w;
    }
    float ab[4][8];
#pragma unroll
    for (int j = 0; j < 8; ++j) {
        const float4* ap = reinterpret_cast<const float4*>(A + (size_t)(k0 + j) * LORA_R);
        float4 a0 = ap[0], a1 = ap[1], a2 = ap[2], a3 = ap[3];
        float av[16] = {a0.x,a0.y,a0.z,a0.w,a1.x,a1.y,a1.z,a1.w,
                        a2.x,a2.y,a2.z,a2.w,a3.x,a3.y,a3.z,a3.w};
#pragma unroll
        for (int n = 0; n < 4; ++n) {
            float s = 0.f;
#pragma unroll
            for (int r = 0; r < 16; ++r) s += av[r] * bn[n][r];
            ab[n][j] = s;
        }
    }
#pragma unroll
    for (int n = 0; n < 4; ++n) {
        const float4* wp = reinterpret_cast<const float4*>(W + (size_t)(n0 + n) * DIM + k0);
        float4 w0 = wp[0], w1 = wp[1];
        float wv[8] = {w0.x,w0.y,w0.z,w0.w,w1.x,w1.y,w1.z,w1.w};
        union { bf16_t o[8]; uint4 u; } pk;
#pragma unroll
        for (int j = 0; j < 8; ++j) pk.o[j] = (bf16_t)(wv[j] + LORA_SCALE * ab[n][j]);
        *reinterpret_cast<uint4*>(Wt + (size_t)(n0 + n) * DIM + k0) = pk.u;
    }
}

// ---------------------------------------------------------------------------
// Kernel 3: 256x256 GEMM — R2's exact 4-interval snake schedule (validated),
// ONLY change: MFMA shape 16x16x32 -> 32x32x16.
// C[m][n] = sum_k Xb[m][k]*Wt[n][k] + bias[n]
// 512 thr = 8 waves (2M x 4N); per-wave 128x64 out = acc[4][2] 32x32 frags
// (m-blocks 0-3 of 32 rows, n-blocks 0-1 of 32 cols, ks 0-3 of k=16).
// LDS: 2 dbuf x (A 256x64 + B 256x64) bf16 = 128 KiB.  Swizzle (verified 0
// conflicts R1-R3): linear LDS dest + inverse-swizzled global src; ds_read
// col-slot = (2*ks + (lane>>5)) ^ (lane&7), 8-elem granules.
//
//   I0: read bHi(d) [4]        | MFMA m01 x n0 (aLo,bLo)  [8]
//   I1: read aHi(d) [8], STAGE_B(t+2)->d | MFMA m01 x n1 (aLo,bHi) | vmcnt(4)
//   I2: read aLo(d^1) [8], STAGE_A(t+2)->d | MFMA m23 x n1 (aHi,bHi)
//   I3: MFMA m23 x n0 (aHi,bLo) | read bLo(d^1) [4]
// Hazard discipline (R2-proven): every LDS region's reads are issued >=1
// barrier before its overwrite issues, and consumers lgkm-retire before the
// intervening barrier.  vmcnt(4) lands tile t+1's 8 loads, keeps 4 in flight.
// ---------------------------------------------------------------------------
#define BM 256
#define BN 256
#define BK 64
#define MB_BLKS (TOKENS / BM)    // 32
#define NB_BLKS (DIM_OUT / BN)   // 16
#define NT      (DIM / BK)       // 64 K-tiles

#define SB0() __builtin_amdgcn_sched_barrier(0)
#define BAR() do { __builtin_amdgcn_s_barrier(); SB0(); } while (0)
#define VMWAIT_(n) asm volatile("s_waitcnt vmcnt(" #n ")" ::: "memory")
#define VMWAIT(n) VMWAIT_(n)

__global__ __launch_bounds__(512, 2) void gemm_kernel(
    const bf16_t* __restrict__ Xb, const bf16_t* __restrict__ Wt,
    const float* __restrict__ bias, float* __restrict__ C)
{
    __shared__ __align__(16) bf16_t sA[2][BM][BK];   // 64 KiB
    __shared__ __align__(16) bf16_t sB[2][BN][BK];   // 64 KiB

    const int nwg = MB_BLKS * NB_BLKS;               // 512, %8==0 -> bijective
    int bid = blockIdx.x;
    int swz = (bid & 7) * (nwg >> 3) + (bid >> 3);   // XCD-aware remap
    int bm = swz / NB_BLKS;
    int bn = swz % NB_BLKS;

    const int tid  = threadIdx.x;
    const int lane = tid & 63;
    const int wid  = tid >> 6;       // 0..7
    const int wr   = wid >> 2;       // 0..1  (M half: 128 rows)
    const int wc   = wid & 3;        // 0..3  (N quarter: 64 cols)

    // ---- staging constants (linear LDS dest, pre-swizzled global src) ----
    const int srow = tid >> 3;                       // 0..63
    const int scol = (tid & 7) * 8;                  // linear col (elems)
    const int koff = (((tid & 7) ^ ((tid >> 3) & 7)) * 8); // swizzled src col
    const bf16_t* Ag = Xb + (size_t)(bm * BM + srow) * DIM + koff;
    const bf16_t* Bg = Wt + (size_t)(bn * BN + srow) * DIM + koff;

#define STAGE_A(dd, kt) do { \
    const bf16_t* s_ = Ag + (size_t)(kt) * BK; \
    bf16_t* d_ = &sA[dd][srow][scol]; \
    gload_lds16(s_,                     d_); \
    gload_lds16(s_ + (size_t)64  * DIM, d_ + 64  * BK); \
    gload_lds16(s_ + (size_t)128 * DIM, d_ + 128 * BK); \
    gload_lds16(s_ + (size_t)192 * DIM, d_ + 192 * BK); \
} while (0)

#define STAGE_B(dd, kt) do { \
    const bf16_t* s_ = Bg + (size_t)(kt) * BK; \
    bf16_t* d_ = &sB[dd][srow][scol]; \
    gload_lds16(s_,                     d_); \
    gload_lds16(s_ + (size_t)64  * DIM, d_ + 64  * BK); \
    gload_lds16(s_ + (size_t)128 * DIM, d_ + 128 * BK); \
    gload_lds16(s_ + (size_t)192 * DIM, d_ + 192 * BK); \
} while (0)

    // ---- fragment-read constants (swizzled, 32x32 layout) ----
    const int q   = lane & 7;
    const int kgl = lane >> 5;                       // 0..1 (k-half in instr)
    const int r31 = lane & 31;
    int cS[4];
#pragma unroll
    for (int s = 0; s < 4; ++s) cS[s] = ((2 * s + kgl) ^ q) * 8;
    const int arow0 = wr * 128 + r31;                // + m*32
    const int brow0 = wc * 64  + r31;                // + n*32

    f32x16 acc[4][2] = {};
    bfrag aLo[2][4], aHi[2][4], bLo[4], bHi[4];      // [blk][ks] / [ks]

#define READ_A2(dst, dd, mb0) do { \
    _Pragma("unroll") \
    for (int m_ = 0; m_ < 2; ++m_) \
    _Pragma("unroll") \
    for (int s_ = 0; s_ < 4; ++s_) \
        dst[m_][s_] = *reinterpret_cast<const bfrag*>( \
            &sA[dd][arow0 + (mb0 + m_) * 32][cS[s_]]); \
} while (0)

#define READ_B1(dst, dd, nb) do { \
    _Pragma("unroll") \
    for (int s_ = 0; s_ < 4; ++s_) \
        dst[s_] = *reinterpret_cast<const bfrag*>( \
            &sB[dd][brow0 + (nb) * 32][cS[s_]]); \
} while (0)

// 8 MFMA: m-blocks {mb0,mb0+1} x one n-block x ks0-3
#define MFMA_Q(Af, Bf, mb0, nb) do { \
    __builtin_amdgcn_s_setprio(1); \
    _Pragma("unroll") \
    for (int s_ = 0; s_ < 4; ++s_) \
    _Pragma("unroll") \
    for (int m_ = 0; m_ < 2; ++m_) \
        acc[mb0 + m_][nb] = __builtin_amdgcn_mfma_f32_32x32x16_bf16( \
            Af[m_][s_], Bf[s_], acc[mb0 + m_][nb], 0, 0, 0); \
    __builtin_amdgcn_s_setprio(0); \
} while (0)

// One K-tile (buffer d).  S: stage tile ktn -> buffer d.
// NEXT: prefetch next tile's frags from buffer d^1.  VM: vmcnt at I1.
#define TILE(d, ktn, S, NEXT, VM) do { \
    /* I0 */ READ_B1(bHi, d, 1); \
             SB0(); MFMA_Q(aLo, bLo, 0, 0); BAR(); \
    /* I1 */ READ_A2(aHi, d, 2); if (S) STAGE_B(d, ktn); \
             SB0(); MFMA_Q(aLo, bHi, 0, 1); VMWAIT(VM); BAR(); \
    /* I2 */ if (NEXT) READ_A2(aLo, (d) ^ 1, 0); if (S) STAGE_A(d, ktn); \
             SB0(); MFMA_Q(aHi, bHi, 2, 1); BAR(); \
    /* I3 */ MFMA_Q(aHi, bLo, 2, 0); \
             if (NEXT) READ_B1(bLo, (d) ^ 1, 0); BAR(); \
} while (0)

    // ---- prologue: tiles 0,1 staged; tile0's first-half frags in regs ----
    STAGE_A(0, 0); STAGE_B(0, 0);
    STAGE_B(1, 1); STAGE_A(1, 1);
    VMWAIT(8);          // tile 0 landed; tile 1's 8 loads stay in flight
    BAR();
    READ_A2(aLo, 0, 0); READ_B1(bLo, 0, 0);

    // ---- main loop: tiles 0..61 (31 iterations x 2), staging t+2 ----
    for (int it = 0; it < NT / 2 - 1; ++it) {
        int kt0 = 2 * it;
        TILE(0, kt0 + 2, true, true, 4);
        TILE(1, kt0 + 3, true, true, 4);
    }
    // ---- peeled tiles 62, 63 ----
    TILE(0, 0, false, true, 0);    // drain: tile 63's loads must land
    TILE(1, 0, false, false, 0);

    // ---- epilogue: 32x32 D layout col=lane&31, row=(reg&3)+8*(reg>>2)+4*(lane>>5) ----
    const int colbase = bn * BN + wc * 64 + r31;
    const int rowbase = bm * BM + wr * 128 + 4 * kgl;
#pragma unroll
    for (int n = 0; n < 2; ++n) {
        int c = colbase + n * 32;
        float bv = bias[c];
#pragma unroll
        for (int m = 0; m < 4; ++m) {
            int rb = rowbase + m * 32;
#pragma unroll
            for (int reg = 0; reg < 16; ++reg) {
                int r = rb + (reg & 3) + 8 * (reg >> 2);
                C[(size_t)r * DIM_OUT + c] = acc[m][n][reg] + bv;
            }
        }
    }
}

// ---------------------------------------------------------------------------
extern "C" void kernel_launch(void* const* d_in, const int* in_sizes, int n_in,
                              void* d_out, int out_size, void* d_ws, size_t ws_size,
                              hipStream_t stream) {
    const float* x = (const float*)d_in[0];
    const float* A = (const float*)d_in[1];
    const float* B = (const float*)d_in[2];
    const float* W = (const float*)d_in[3];
    const float* b = (const float*)d_in[4];
    float* out = (float*)d_out;

    // workspace: xb (8192*4096 bf16 = 64MB) | Wt (4096*4096 bf16 = 32MB)
    bf16_t* xb = (bf16_t*)d_ws;
    bf16_t* Wt = (bf16_t*)((char*)d_ws + (size_t)TOKENS * DIM * 2);

    cast_x_kernel<<<2048, 256, 0, stream>>>(x, xb);
    weff_kernel<<<(DIM_OUT * DIM / 32) / 256, 256, 0, stream>>>(W, A, B, Wt);
    gemm_kernel<<<MB_BLKS * NB_BLKS, 512, 0, stream>>>(xb, Wt, b, out);
}

// Round 7
// 325.406 us; speedup vs baseline: 1.0659x; 1.0659x over previous
//
#include <hip/hip_runtime.h>
#include <hip/hip_bf16.h>
#include <stdint.h>

// Problem constants (reference: LoRA adapter forward)
#define TOKENS   8192
#define DIM      4096
#define DIM_OUT  4096
#define LORA_R   16
#define LORA_SCALE 2.0f

typedef __bf16 bf16_t;
typedef __attribute__((ext_vector_type(8))) __bf16 bfrag;   // 8 bf16 = 4 VGPR (MFMA A/B frag)
typedef __attribute__((ext_vector_type(4))) float f32x4;    // MFMA C/D frag

// ---------------------------------------------------------------------------
// async global->LDS, 16B per lane (global_load_lds_dwordx4)
// ---------------------------------------------------------------------------
__device__ __forceinline__ void gload_lds16(const bf16_t* gsrc, bf16_t* ldst) {
    __builtin_amdgcn_global_load_lds(
        (const __attribute__((address_space(1))) uint32_t*)(const void*)gsrc,
        (__attribute__((address_space(3))) uint32_t*)(void*)ldst,
        16, 0, 0);
}

// ---------------------------------------------------------------------------
// Kernel 1: fused prep (R4-validated form).
// Blocks [0,2048): cast x fp32->bf16.  Blocks [2048,4096): Weff.
// ---------------------------------------------------------------------------
#define CAST_BLOCKS 2048
__global__ void prep_kernel(const float* __restrict__ x, bf16_t* __restrict__ xb,
                            const float* __restrict__ W, const float* __restrict__ A,
                            const float* __restrict__ B, bf16_t* __restrict__ Wt) {
    if (blockIdx.x < CAST_BLOCKS) {
        const int total = TOKENS * DIM / 8;
        for (int i = blockIdx.x * blockDim.x + threadIdx.x; i < total;
             i += CAST_BLOCKS * 256) {
            const float4* p = reinterpret_cast<const float4*>(x + (size_t)i * 8);
            float4 v0 = p[0], v1 = p[1];
            union { bf16_t o[8]; uint4 u; } pk;
            pk.o[0] = (bf16_t)v0.x; pk.o[1] = (bf16_t)v0.y;
            pk.o[2] = (bf16_t)v0.z; pk.o[3] = (bf16_t)v0.w;
            pk.o[4] = (bf16_t)v1.x; pk.o[5] = (bf16_t)v1.y;
            pk.o[6] = (bf16_t)v1.z; pk.o[7] = (bf16_t)v1.w;
            *reinterpret_cast<uint4*>(xb + (size_t)i * 8) = pk.u;
        }
    } else {
        int idx = (blockIdx.x - CAST_BLOCKS) * blockDim.x + threadIdx.x;
        int k0 = (idx & 511) << 3;          // 512 k-groups of 8
        int n0 = (idx >> 9) << 2;           // 1024 n-groups of 4

        float bn[4][16];
#pragma unroll
        for (int r = 0; r < 16; ++r) {
            float4 bv = *reinterpret_cast<const float4*>(B + (size_t)r * DIM_OUT + n0);
            bn[0][r] = bv.x; bn[1][r] = bv.y; bn[2][r] = bv.z; bn[3][r] = bv.w;
        }
        float ab[4][8];
#pragma unroll
        for (int j = 0; j < 8; ++j) {
            const float4* ap = reinterpret_cast<const float4*>(A + (size_t)(k0 + j) * LORA_R);
            float4 a0 = ap[0], a1 = ap[1], a2 = ap[2], a3 = ap[3];
            float av[16] = {a0.x,a0.y,a0.z,a0.w,a1.x,a1.y,a1.z,a1.w,
                            a2.x,a2.y,a2.z,a2.w,a3.x,a3.y,a3.z,a3.w};
#pragma unroll
            for (int n = 0; n < 4; ++n) {
                float s = 0.f;
#pragma unroll
                for (int r = 0; r < 16; ++r) s += av[r] * bn[n][r];
                ab[n][j] = s;
            }
        }
#pragma unroll
        for (int n = 0; n < 4; ++n) {
            const float4* wp = reinterpret_cast<const float4*>(W + (size_t)(n0 + n) * DIM + k0);
            float4 w0 = wp[0], w1 = wp[1];
            float wv[8] = {w0.x,w0.y,w0.z,w0.w,w1.x,w1.y,w1.z,w1.w};
            union { bf16_t o[8]; uint4 u; } pk;
#pragma unroll
            for (int j = 0; j < 8; ++j) pk.o[j] = (bf16_t)(wv[j] + LORA_SCALE * ab[n][j]);
            *reinterpret_cast<uint4*>(Wt + (size_t)(n0 + n) * DIM + k0) = pk.u;
        }
    }
}

// ---------------------------------------------------------------------------
// Kernel 2: 256x256 GEMM.  R2's validated 16x16x32 snake schedule with the
// I3+I0 intervals MERGED -> 3 barriers per K-tile (was 4).
// C[m][n] = sum_k Xb[m][k]*Wt[n][k] + bias[n]
// 512 thr = 8 waves (2M x 4N); per-wave 128x64 out = acc[8][4] 16x16 frags.
// LDS: 2 dbuf x (A 256x64 + B 256x64) bf16 = 128 KiB.  Swizzle (0 conflicts,
// R1-R3 measured): linear LDS dest + inverse-swizzled global src; ds_read
// col = ((ks*4 + (lane>>4)) ^ (lane&7)) * 8.
//
// Per K-tile t (buffer d), 3 intervals:
//  J1: read aHi(d)[8]; STAGE_B(d,t+2); MFMA Q01(aLo,bHi); vmcnt(4); bar
//  J2: read aLo(d^1)[8]; STAGE_A(d,t+2); MFMA Q11(aHi,bHi); bar
//  M : MFMA Q10(aHi,bLo); read bLo(d^1)[4], bHi(d^1)[4];
//      MFMA Q00(aLo',bLo')  [tile t+1's first quadrant]; bar
// WAR on b-regs in M: Q10 issues before the overwriting reads (program
// order / SSA). Q00's lgkm wait hides under Q10's pipe drain.
// Hazards: every sX[d] region's reads issue >=1 barrier before its
// overwrite issues; stage writes land >=1 tile later (vmcnt discipline).
// vmcnt(4) at J1 lands tile t+1's 8 loads before J2/M read buffer d^1.
// ---------------------------------------------------------------------------
#define BM 256
#define BN 256
#define BK 64
#define MB_BLKS (TOKENS / BM)    // 32
#define NB_BLKS (DIM_OUT / BN)   // 16
#define NT      (DIM / BK)       // 64 K-tiles

#define SB0() __builtin_amdgcn_sched_barrier(0)
#define BAR() do { __builtin_amdgcn_s_barrier(); SB0(); } while (0)
#define VMWAIT_(n) asm volatile("s_waitcnt vmcnt(" #n ")" ::: "memory")
#define VMWAIT(n) VMWAIT_(n)

__global__ __launch_bounds__(512, 2) void gemm_kernel(
    const bf16_t* __restrict__ Xb, const bf16_t* __restrict__ Wt,
    const float* __restrict__ bias, float* __restrict__ C)
{
    __shared__ __align__(16) bf16_t sA[2][BM][BK];   // 64 KiB
    __shared__ __align__(16) bf16_t sB[2][BN][BK];   // 64 KiB

    const int nwg = MB_BLKS * NB_BLKS;               // 512, %8==0 -> bijective
    int bid = blockIdx.x;
    int swz = (bid & 7) * (nwg >> 3) + (bid >> 3);   // XCD-aware remap
    int bm = swz / NB_BLKS;
    int bn = swz % NB_BLKS;

    const int tid  = threadIdx.x;
    const int lane = tid & 63;
    const int wid  = tid >> 6;       // 0..7
    const int wr   = wid >> 2;       // 0..1  (M half: 128 rows)
    const int wc   = wid & 3;        // 0..3  (N quarter: 64 cols)

    // ---- staging constants (linear LDS dest, pre-swizzled global src) ----
    const int srow = tid >> 3;                       // 0..63
    const int scol = (tid & 7) * 8;                  // linear col (elems)
    const int koff = (((tid & 7) ^ ((tid >> 3) & 7)) * 8); // swizzled src col
    const bf16_t* Ag = Xb + (size_t)(bm * BM + srow) * DIM + koff;
    const bf16_t* Bg = Wt + (size_t)(bn * BN + srow) * DIM + koff;

#define STAGE_A(dd, kt) do { \
    const bf16_t* s_ = Ag + (size_t)(kt) * BK; \
    bf16_t* d_ = &sA[dd][srow][scol]; \
    gload_lds16(s_,                     d_); \
    gload_lds16(s_ + (size_t)64  * DIM, d_ + 64  * BK); \
    gload_lds16(s_ + (size_t)128 * DIM, d_ + 128 * BK); \
    gload_lds16(s_ + (size_t)192 * DIM, d_ + 192 * BK); \
} while (0)

#define STAGE_B(dd, kt) do { \
    const bf16_t* s_ = Bg + (size_t)(kt) * BK; \
    bf16_t* d_ = &sB[dd][srow][scol]; \
    gload_lds16(s_,                     d_); \
    gload_lds16(s_ + (size_t)64  * DIM, d_ + 64  * BK); \
    gload_lds16(s_ + (size_t)128 * DIM, d_ + 128 * BK); \
    gload_lds16(s_ + (size_t)192 * DIM, d_ + 192 * BK); \
} while (0)

    // ---- fragment-read constants (swizzled) ----
    const int q     = lane & 7;
    const int kslot = lane >> 4;                     // 0..3
    const int r15   = lane & 15;
    const int cK0   = ((kslot    ) ^ q) * 8;         // ks=0 col (elems)
    const int cK1   = ((kslot + 4) ^ q) * 8;         // ks=1 col (elems)
    const int arow0 = wr * 128 + r15;                // + m*16
    const int brow0 = wc * 64  + r15;                // + n*16

    f32x4 acc[8][4] = {};
    bfrag aLo[4][2], aHi[4][2], bLo[2][2], bHi[2][2];

#define READ_A4(dst, dd, mb) do { \
    _Pragma("unroll") \
    for (int m_ = 0; m_ < 4; ++m_) { \
        dst[m_][0] = *reinterpret_cast<const bfrag*>(&sA[dd][arow0 + (mb + m_) * 16][cK0]); \
        dst[m_][1] = *reinterpret_cast<const bfrag*>(&sA[dd][arow0 + (mb + m_) * 16][cK1]); \
    } \
} while (0)

#define READ_B2(dst, dd, nb) do { \
    _Pragma("unroll") \
    for (int n_ = 0; n_ < 2; ++n_) { \
        dst[n_][0] = *reinterpret_cast<const bfrag*>(&sB[dd][brow0 + (nb + n_) * 16][cK0]); \
        dst[n_][1] = *reinterpret_cast<const bfrag*>(&sB[dd][brow0 + (nb + n_) * 16][cK1]); \
    } \
} while (0)

#define MFMA_Q(Af, Bf, mb, nb) do { \
    __builtin_amdgcn_s_setprio(1); \
    _Pragma("unroll") \
    for (int m_ = 0; m_ < 4; ++m_) \
    _Pragma("unroll") \
    for (int n_ = 0; n_ < 2; ++n_) \
    _Pragma("unroll") \
    for (int ks_ = 0; ks_ < 2; ++ks_) \
        acc[mb + m_][nb + n_] = __builtin_amdgcn_mfma_f32_16x16x32_bf16( \
            Af[m_][ks_], Bf[n_][ks_], acc[mb + m_][nb + n_], 0, 0, 0); \
    __builtin_amdgcn_s_setprio(0); \
} while (0)

// One K-tile (buffer d), 3 intervals.  S: stage tile ktn -> buffer d.
// NEXTQ: read tile t+1's b-frags and do its Q00.  VM: vmcnt at J1.
#define TILE3(d, ktn, S, NEXTQ, VM) do { \
    /* J1 */ READ_A4(aHi, d, 4); if (S) STAGE_B(d, ktn); \
             SB0(); MFMA_Q(aLo, bHi, 0, 2); VMWAIT(VM); BAR(); \
    /* J2 */ if (NEXTQ) READ_A4(aLo, (d) ^ 1, 0); if (S) STAGE_A(d, ktn); \
             SB0(); MFMA_Q(aHi, bHi, 4, 2); BAR(); \
    /* M  */ MFMA_Q(aHi, bLo, 4, 0); \
             if (NEXTQ) { \
                 READ_B2(bLo, (d) ^ 1, 0); READ_B2(bHi, (d) ^ 1, 2); \
                 MFMA_Q(aLo, bLo, 0, 0); \
             } \
             BAR(); \
} while (0)

    // ---- prologue: tiles 0,1 staged; tile0's Q00 done here ----
    STAGE_A(0, 0); STAGE_B(0, 0);
    STAGE_B(1, 1); STAGE_A(1, 1);
    VMWAIT(8);          // tile 0 landed; tile 1's 8 loads stay in flight
    BAR();
    READ_A4(aLo, 0, 0); READ_B2(bLo, 0, 0); READ_B2(bHi, 0, 2);
    SB0();
    MFMA_Q(aLo, bLo, 0, 0);      // Q00(tile 0)
    BAR();                       // all waves' prologue reads issued before
                                 // any wave's J1 stage issues

    // ---- main loop: tiles 0..61 (31 iterations x 2), staging t+2 ----
    for (int it = 0; it < NT / 2 - 1; ++it) {
        int kt0 = 2 * it;
        TILE3(0, kt0 + 2, true, true, 4);
        TILE3(1, kt0 + 3, true, true, 4);
    }
    // ---- peeled tiles 62, 63 (fully staged; Q00(62) done at it=30's M) ----
    TILE3(0, 0, false, true, 0);   // VM(0): drain tile 63's loads
    TILE3(1, 0, false, false, 0);

    // ---- epilogue: D layout row=(lane>>4)*4+j, col=lane&15 ----
    int row0 = bm * BM + wr * 128 + (lane >> 4) * 4;
    int col0 = bn * BN + wc * 64 + r15;
#pragma unroll
    for (int n = 0; n < 4; ++n) {
        int c = col0 + n * 16;
        float bv = bias[c];
#pragma unroll
        for (int m = 0; m < 8; ++m) {
            int r = row0 + m * 16;
#pragma unroll
            for (int j = 0; j < 4; ++j)
                C[(size_t)(r + j) * DIM_OUT + c] = acc[m][n][j] + bv;
        }
    }
}

// ---------------------------------------------------------------------------
extern "C" void kernel_launch(void* const* d_in, const int* in_sizes, int n_in,
                              void* d_out, int out_size, void* d_ws, size_t ws_size,
                              hipStream_t stream) {
    const float* x = (const float*)d_in[0];
    const float* A = (const float*)d_in[1];
    const float* B = (const float*)d_in[2];
    const float* W = (const float*)d_in[3];
    const float* b = (const float*)d_in[4];
    float* out = (float*)d_out;

    // workspace: xb (8192*4096 bf16 = 64MB) | Wt (4096*4096 bf16 = 32MB)
    bf16_t* xb = (bf16_t*)d_ws;
    bf16_t* Wt = (bf16_t*)((char*)d_ws + (size_t)TOKENS * DIM * 2);

    prep_kernel<<<CAST_BLOCKS + 2048, 256, 0, stream>>>(x, xb, W, A, B, Wt);
    gemm_kernel<<<MB_BLKS * NB_BLKS, 512, 0, stream>>>(xb, Wt, b, out);
}